// Round 1
// baseline (684.267 us; speedup 1.0000x reference)
//
#include <hip/hip_runtime.h>
#include <cstdint>
#include <cstddef>

// ---------------------------------------------------------------------------
// StyleDownBlock: styles -> demod -> (blur4x4 ∘ conv3x3 stride2 grouped) -> lrelu
// N=16, I=256, O=512, H=W=64, out 16x512x32x32 fp32.
// Strategy: bf16 MFMA implicit GEMM (per-sample M=512,N=1024,K=2304),
// channel-last packed operands so all staging is global_load_lds dwordx4.
// ---------------------------------------------------------------------------

typedef short bf16x8 __attribute__((ext_vector_type(8)));
typedef float f32x4  __attribute__((ext_vector_type(4)));

__device__ __forceinline__ unsigned short f2bf(float f) {
  union { float f; unsigned u; } v; v.f = f;
  unsigned r = (v.u + 0x7FFFu + ((v.u >> 16) & 1u)) >> 16;  // RNE
  return (unsigned short)r;
}

__device__ __forceinline__ void gload_lds16(const void* g, void* l) {
  __builtin_amdgcn_global_load_lds((const __attribute__((address_space(1))) void*)g,
                                   (__attribute__((address_space(3))) void*)l,
                                   16, 0, 0);
}

// ---- stage 1: styles[n,i] = dot(w[n,:], affine_w[i,:])/sqrt(512) + affine_b[i]
__global__ void styles_kernel(const float* __restrict__ w, const float* __restrict__ aw,
                              const float* __restrict__ ab, float* __restrict__ styles) {
  const int n = blockIdx.x;      // 16
  const int i = threadIdx.x;     // 256
  const float4* wr = (const float4*)(w + (size_t)n * 512);
  const float4* ar = (const float4*)(aw + (size_t)i * 512);
  float acc = 0.f;
#pragma unroll 4
  for (int k = 0; k < 128; ++k) {
    float4 a = wr[k], c = ar[k];
    acc += a.x * c.x + a.y * c.y + a.z * c.z + a.w * c.w;
  }
  styles[n * 256 + i] = acc * 0.04419417382415922f + ab[i];  // 1/sqrt(512)
}

// ---- stage 2a: wsq[o,i] = sum_k weight[o,i,k]^2
__global__ void wsq_kernel(const float* __restrict__ wt, float* __restrict__ wsq) {
  const int o = blockIdx.x;      // 512
  const int i = threadIdx.x;     // 256
  const float* p = wt + ((size_t)o * 256 + i) * 9;
  float s = 0.f;
#pragma unroll
  for (int k = 0; k < 9; ++k) s += p[k] * p[k];
  wsq[o * 256 + i] = s;
}

// ---- stage 2b: dcoefs[n,o] = rsqrt(sum_i wsq[o,i]*styles[n,i]^2 + 1e-8)
__global__ void dcoefs_kernel(const float* __restrict__ wsq, const float* __restrict__ styles,
                              float* __restrict__ dcoefs) {
  __shared__ float st2[256];
  const int n = blockIdx.x;      // 16
  const int t = threadIdx.x;     // 512
  if (t < 256) { float s = styles[n * 256 + t]; st2[t] = s * s; }
  __syncthreads();
  const float4* wr = (const float4*)(wsq + (size_t)t * 256);
  const float4* sr = (const float4*)st2;
  float acc = 0.f;
#pragma unroll 4
  for (int k = 0; k < 64; ++k) {
    float4 a = wr[k], c = sr[k];
    acc += a.x * c.x + a.y * c.y + a.z * c.z + a.w * c.w;
  }
  dcoefs[n * 512 + t] = 1.0f / sqrtf(acc + 1e-8f);
}

// ---- stage 3: Amod[n][tap][o][i] = bf16(weight[o,i,flip(tap)] * styles * dcoefs)
// tap = kh*3+kw of the CORRELATION kernel; flipped index = 8 - tap.
__global__ void modw_kernel(const float* __restrict__ wt, const float* __restrict__ styles,
                            const float* __restrict__ dcoefs, unsigned short* __restrict__ Amod) {
  const int b = blockIdx.x;      // 16*512
  const int n = b >> 9;
  const int o = b & 511;
  const int i = threadIdx.x;     // 256
  const float sd = styles[n * 256 + i] * dcoefs[n * 512 + o];
  const float* p = wt + ((size_t)o * 256 + i) * 9;
  float wv[9];
#pragma unroll
  for (int k = 0; k < 9; ++k) wv[k] = p[k];
#pragma unroll
  for (int t = 0; t < 9; ++t)
    Amod[((size_t)(n * 9 + t) * 512 + o) * 256 + i] = f2bf(wv[8 - t] * sd);
}

// ---- stage 4: separable 4x4 blur, pad 2, bf16 out in parity-split channel-last:
// xfp[n][ph][pw][r(33)][c(33)][i(256)], element = xf[n,i, 2r+ph, 2c+pw]
__global__ void blur_kernel(const float* __restrict__ x, unsigned short* __restrict__ xfp) {
  const int b = blockIdx.x;             // 16 * 17 * 4
  const int n = b / 68;
  const int rem = b - n * 68;
  const int yg = rem >> 2;              // 0..16  (4 output rows each)
  const int cg = rem & 3;               // channel group of 64
  const int i = cg * 64 + threadIdx.x;  // 64 threads = 1 wave
  const float* xin = x + ((size_t)n * 256 + i) * 4096;
  const float F0 = 0.125f, F1 = 0.375f, F2 = 0.375f, F3 = 0.125f;
  const int ybase = yg * 4;

  float w0[4], w1[4], w2[4];
  auto vcol = [&](int col, float* v) {
    float r[7];
#pragma unroll
    for (int j = 0; j < 7; ++j) {
      int rj = ybase - 2 + j;
      r[j] = ((unsigned)rj < 64u && (unsigned)col < 64u) ? xin[rj * 64 + col] : 0.f;
    }
#pragma unroll
    for (int dy = 0; dy < 4; ++dy)
      v[dy] = F0 * r[dy] + F1 * r[dy + 1] + F2 * r[dy + 2] + F3 * r[dy + 3];
  };
  vcol(-2, w0); vcol(-1, w1); vcol(0, w2);
  for (int xo = 0; xo <= 64; ++xo) {
    float w3[4];
    vcol(xo + 1, w3);
    const int pwp = xo & 1, c = xo >> 1;
#pragma unroll
    for (int dy = 0; dy < 4; ++dy) {
      int y = ybase + dy;
      if (y <= 64) {
        float o = F0 * w0[dy] + F1 * w1[dy] + F2 * w2[dy] + F3 * w3[dy];
        int phh = y & 1, rr = y >> 1;
        xfp[((((size_t)(n * 2 + phh) * 2 + pwp) * 33 + rr) * 33 + c) * 256 + i] = f2bf(o);
      }
    }
#pragma unroll
    for (int dy = 0; dy < 4; ++dy) { w0[dy] = w1[dy]; w1[dy] = w2[dy]; w2[dy] = w3[dy]; }
  }
}

// ---- stage 5: main conv. grid 512 = n(16) x om(4) x pt(8).
// block 256 thr = 4 waves (2x2), 128(M=o) x 128(N=pos) tile, K = 9 taps x 8 k-blocks of 32ch.
__global__ __launch_bounds__(256, 2) void conv_kernel(
    const unsigned short* __restrict__ Amod,
    const unsigned short* __restrict__ xfp,
    const float* __restrict__ bias,
    float* __restrict__ out) {
  __shared__ unsigned short Als[128 * 32];  // [o_row][k] k-contiguous
  __shared__ unsigned short Bls[128 * 32];  // [pos][k]  k-contiguous
  const int b = blockIdx.x;
  const int n = b >> 5;
  const int om = (b >> 3) & 3;
  const int pt = b & 7;
  const int o0 = om << 7;
  const int oh0 = pt << 2;
  const int tid = threadIdx.x;
  const int lane = tid & 63;
  const int wv = tid >> 6;
  const int wm = wv >> 1;   // wave's M half
  const int wp = wv & 1;    // wave's N half
  const int ml = lane & 15;
  const int kq = lane >> 4;

  f32x4 acc[4][4];
  const f32x4 zz = {0.f, 0.f, 0.f, 0.f};
#pragma unroll
  for (int i = 0; i < 4; ++i)
#pragma unroll
    for (int j = 0; j < 4; ++j) acc[i][j] = zz;

  // staging slots: slot s = 16B = (row = s>>2, kgroup = s&3); wave wv covers s in [wv*128, wv*128+128)
  const int s0 = wv * 128 + lane;
  const int s1 = s0 + 64;
  const int r0 = s0 >> 2, g0 = (s0 & 3) * 8;
  const int r1 = s1 >> 2, g1 = (s1 & 3) * 8;
  unsigned short* aL0 = Als + wv * 1024;          // wave-uniform LDS bases
  unsigned short* aL1 = Als + wv * 1024 + 512;
  unsigned short* bL0 = Bls + wv * 1024;
  unsigned short* bL1 = Bls + wv * 1024 + 512;

#pragma unroll 1
  for (int tap = 0; tap < 9; ++tap) {
    const int kh = (tap >= 6) ? 2 : ((tap >= 3) ? 1 : 0);
    const int kw = tap - kh * 3;
    const int ph = kh & 1, dr = kh >> 1;
    const int pw = kw & 1, dc = kw >> 1;
    const unsigned short* Atap = Amod + (((size_t)(n * 9 + tap) * 512 + o0) << 8);
    const unsigned short* Bpl  = xfp + ((size_t)(((n * 2 + ph) * 2 + pw) * 1089) << 8);
    const unsigned short* Ag0 = Atap + ((size_t)r0 << 8) + g0;
    const unsigned short* Ag1 = Atap + ((size_t)r1 << 8) + g1;
    const unsigned short* Bg0 = Bpl + ((size_t)((oh0 + (r0 >> 5) + dr) * 33 + (r0 & 31) + dc) << 8) + g0;
    const unsigned short* Bg1 = Bpl + ((size_t)((oh0 + (r1 >> 5) + dr) * 33 + (r1 & 31) + dc) << 8) + g1;
#pragma unroll 1
    for (int kb = 0; kb < 8; ++kb) {
      const int ko = kb << 5;
      __syncthreads();                       // prev iter done reading LDS
      gload_lds16(Ag0 + ko, aL0);
      gload_lds16(Ag1 + ko, aL1);
      gload_lds16(Bg0 + ko, bL0);
      gload_lds16(Bg1 + ko, bL1);
      __syncthreads();                       // drains vmcnt; LDS tile ready
      bf16x8 af[4], bfv[4];
      const bf16x8* A8 = (const bf16x8*)Als;
      const bf16x8* B8 = (const bf16x8*)Bls;
#pragma unroll
      for (int t = 0; t < 4; ++t) {
        af[t]  = A8[(wm * 64 + t * 16 + ml) * 4 + kq];
        bfv[t] = B8[(wp * 64 + t * 16 + ml) * 4 + kq];
      }
#pragma unroll
      for (int mt = 0; mt < 4; ++mt)
#pragma unroll
        for (int nt = 0; nt < 4; ++nt)
          acc[mt][nt] = __builtin_amdgcn_mfma_f32_16x16x32_bf16(af[mt], bfv[nt], acc[mt][nt], 0, 0, 0);
    }
  }

  // epilogue: C/D layout col=lane&15 (pos), row=(lane>>4)*4+reg (o). bias + lrelu*sqrt2.
#pragma unroll
  for (int mt = 0; mt < 4; ++mt) {
#pragma unroll
    for (int nt = 0; nt < 4; ++nt) {
      const int p = wp * 64 + nt * 16 + ml;
      const int oh = oh0 + (p >> 5), ow = p & 31;
#pragma unroll
      for (int r = 0; r < 4; ++r) {
        const int o = o0 + wm * 64 + mt * 16 + kq * 4 + r;
        float v = acc[mt][nt][r] + bias[o];
        v = (v >= 0.f ? v : 0.2f * v) * 1.41421356237309515f;
        out[(((size_t)n * 512 + o) * 32 + oh) * 32 + ow] = v;
      }
    }
  }
}

extern "C" void kernel_launch(void* const* d_in, const int* in_sizes, int n_in,
                              void* d_out, int out_size, void* d_ws, size_t ws_size,
                              hipStream_t stream) {
  const float* x  = (const float*)d_in[0];   // [16,256,64,64]
  const float* w  = (const float*)d_in[1];   // [16,512]
  const float* aw = (const float*)d_in[2];   // [256,512]
  const float* ab = (const float*)d_in[3];   // [256]
  const float* wt = (const float*)d_in[4];   // [512,256,3,3]
  const float* bs = (const float*)d_in[5];   // [512]
  float* out = (float*)d_out;                // [16,512,32,32]

  char* ws = (char*)d_ws;
  float* styles        = (float*)(ws);                       // 16*256*4   = 16 KB
  float* dcoefs        = (float*)(ws + 16384);               // 16*512*4   = 32 KB
  float* wsq           = (float*)(ws + 49152);               // 512*256*4  = 512 KB
  unsigned short* Amod = (unsigned short*)(ws + 573440);     // 16*9*512*256*2 = 37.75 MB
  unsigned short* xfp  = (unsigned short*)(ws + 38322176);   // 16*2*2*33*33*256*2 = 35.68 MB
  // total ws need ~74 MB

  styles_kernel<<<dim3(16),   dim3(256), 0, stream>>>(w, aw, ab, styles);
  wsq_kernel   <<<dim3(512),  dim3(256), 0, stream>>>(wt, wsq);
  dcoefs_kernel<<<dim3(16),   dim3(512), 0, stream>>>(wsq, styles, dcoefs);
  modw_kernel  <<<dim3(8192), dim3(256), 0, stream>>>(wt, styles, dcoefs, Amod);
  blur_kernel  <<<dim3(1088), dim3(64),  0, stream>>>(x, xfp);
  conv_kernel  <<<dim3(512),  dim3(256), 0, stream>>>(Amod, xfp, bs, out);
}

// Round 2
// 311.246 us; speedup vs baseline: 2.1985x; 2.1985x over previous
//
#include <hip/hip_runtime.h>
#include <cstdint>
#include <cstddef>

// ---------------------------------------------------------------------------
// StyleDownBlock: styles -> demod -> (blur4x4 ∘ conv3x3 stride2 grouped) -> lrelu
// N=16, I=256, O=512, H=W=64, out 16x512x32x32 fp32.
// Strategy: bf16 MFMA implicit GEMM (per-sample M=512,N=1024,K=2304),
// channel-last packed operands so all staging is global_load_lds dwordx4.
// R1: blur rewritten with LDS transpose — coalesced NCHW reads, coalesced
// channel-last writes (v0 blur had 24x read amplification, 1.6GB FETCH).
// ---------------------------------------------------------------------------

typedef short bf16x8 __attribute__((ext_vector_type(8)));
typedef float f32x4  __attribute__((ext_vector_type(4)));

__device__ __forceinline__ unsigned short f2bf(float f) {
  union { float f; unsigned u; } v; v.f = f;
  unsigned r = (v.u + 0x7FFFu + ((v.u >> 16) & 1u)) >> 16;  // RNE
  return (unsigned short)r;
}

__device__ __forceinline__ void gload_lds16(const void* g, void* l) {
  __builtin_amdgcn_global_load_lds((const __attribute__((address_space(1))) void*)g,
                                   (__attribute__((address_space(3))) void*)l,
                                   16, 0, 0);
}

// ---- stage 1: styles[n,i] = dot(w[n,:], affine_w[i,:])/sqrt(512) + affine_b[i]
__global__ void styles_kernel(const float* __restrict__ w, const float* __restrict__ aw,
                              const float* __restrict__ ab, float* __restrict__ styles) {
  const int n = blockIdx.x;      // 16
  const int i = threadIdx.x;     // 256
  const float4* wr = (const float4*)(w + (size_t)n * 512);
  const float4* ar = (const float4*)(aw + (size_t)i * 512);
  float acc = 0.f;
#pragma unroll 4
  for (int k = 0; k < 128; ++k) {
    float4 a = wr[k], c = ar[k];
    acc += a.x * c.x + a.y * c.y + a.z * c.z + a.w * c.w;
  }
  styles[n * 256 + i] = acc * 0.04419417382415922f + ab[i];  // 1/sqrt(512)
}

// ---- stage 2a: wsq[o,i] = sum_k weight[o,i,k]^2
__global__ void wsq_kernel(const float* __restrict__ wt, float* __restrict__ wsq) {
  const int o = blockIdx.x;      // 512
  const int i = threadIdx.x;     // 256
  const float* p = wt + ((size_t)o * 256 + i) * 9;
  float s = 0.f;
#pragma unroll
  for (int k = 0; k < 9; ++k) s += p[k] * p[k];
  wsq[o * 256 + i] = s;
}

// ---- stage 2b: dcoefs[n,o] = rsqrt(sum_i wsq[o,i]*styles[n,i]^2 + 1e-8)
__global__ void dcoefs_kernel(const float* __restrict__ wsq, const float* __restrict__ styles,
                              float* __restrict__ dcoefs) {
  __shared__ float st2[256];
  const int n = blockIdx.x;      // 16
  const int t = threadIdx.x;     // 512
  if (t < 256) { float s = styles[n * 256 + t]; st2[t] = s * s; }
  __syncthreads();
  const float4* wr = (const float4*)(wsq + (size_t)t * 256);
  const float4* sr = (const float4*)st2;
  float acc = 0.f;
#pragma unroll 4
  for (int k = 0; k < 64; ++k) {
    float4 a = wr[k], c = sr[k];
    acc += a.x * c.x + a.y * c.y + a.z * c.z + a.w * c.w;
  }
  dcoefs[n * 512 + t] = 1.0f / sqrtf(acc + 1e-8f);
}

// ---- stage 3: Amod[n][tap][o][i] = bf16(weight[o,i,flip(tap)] * styles * dcoefs)
// tap = kh*3+kw of the CORRELATION kernel; flipped index = 8 - tap.
__global__ void modw_kernel(const float* __restrict__ wt, const float* __restrict__ styles,
                            const float* __restrict__ dcoefs, unsigned short* __restrict__ Amod) {
  const int b = blockIdx.x;      // 16*512
  const int n = b >> 9;
  const int o = b & 511;
  const int i = threadIdx.x;     // 256
  const float sd = styles[n * 256 + i] * dcoefs[n * 512 + o];
  const float* p = wt + ((size_t)o * 256 + i) * 9;
  float wv[9];
#pragma unroll
  for (int k = 0; k < 9; ++k) wv[k] = p[k];
#pragma unroll
  for (int t = 0; t < 9; ++t)
    Amod[((size_t)(n * 9 + t) * 512 + o) * 256 + i] = f2bf(wv[8 - t] * sd);
}

// ---- stage 4 (R1 rewrite): separable 4x4 blur, pad 2, bf16 out in parity-split
// channel-last layout: xfp[n][ph][pw][r(33)][c(33)][i(256)] = xf[n,i, 2r+ph, 2c+pw].
// Block = (n, row-group of 13 out rows, channel-group of 64). 256 thr.
// Reads: thread = (ch, 16-col strip) -> 64B contiguous per thread, coalesced.
// Vertical filter in regs (4-row ring); vf row -> LDS [64][69] (stride 69
// breaks 8-way bank conflict); horizontal from LDS, channel-major repack;
// each thread stores bf16x8 (16B), 8 lanes = 128B contiguous.
__global__ __launch_bounds__(256) void blur_kernel(const float* __restrict__ x,
                                                   unsigned short* __restrict__ xfp) {
  __shared__ float vfls[64][69];
  const int b = blockIdx.x;             // 16 * 5 * 4
  const int n = b / 20;
  const int rem = b - n * 20;
  const int rg = rem >> 2;              // 0..4, output rows rg*13 .. rg*13+12
  const int cg = rem & 3;               // channel group of 64
  const int tid = threadIdx.x;
  const int ch = tid >> 2;              // 0..63 local channel
  const int col0 = (tid & 3) * 16;      // 16-col strip
  const float* xin = x + (((size_t)(n * 256 + cg * 64 + ch)) << 12);
  const int ybase = rg * 13;
  const float F0 = 0.125f, F1 = 0.375f;

  float4 ring[4][4];                    // [slot][16 cols]
  auto loadrow = [&](int row) {
    const int slot = row & 3;
    if ((unsigned)row < 64u) {
      const float4* p = (const float4*)(xin + row * 64 + col0);
#pragma unroll
      for (int q = 0; q < 4; ++q) ring[slot][q] = p[q];
    } else {
      const float4 z = {0.f, 0.f, 0.f, 0.f};
#pragma unroll
      for (int q = 0; q < 4; ++q) ring[slot][q] = z;
    }
  };
  loadrow(ybase - 2); loadrow(ybase - 1); loadrow(ybase);

  // zero the horizontal pad columns once
  if ((tid & 3) == 0) { vfls[ch][0] = 0.f; vfls[ch][1] = 0.f; }
  if ((tid & 3) == 3) { vfls[ch][66] = 0.f; vfls[ch][67] = 0.f; vfls[ch][68] = 0.f; }

  for (int yy = 0; yy < 13; ++yy) {
    const int y = ybase + yy;           // 0..64
    loadrow(y + 1);
    // vertical: rows y-2,y-1,y,y+1 -> slots (y+2)&3,(y+3)&3,y&3,(y+1)&3
    const float4* a = ring[(y + 2) & 3];
    const float4* bb = ring[(y + 3) & 3];
    const float4* c = ring[y & 3];
    const float4* d = ring[(y + 1) & 3];
#pragma unroll
    for (int q = 0; q < 4; ++q) {
      float* dst = &vfls[ch][2 + col0 + q * 4];
      dst[0] = F0 * a[q].x + F1 * bb[q].x + F1 * c[q].x + F0 * d[q].x;
      dst[1] = F0 * a[q].y + F1 * bb[q].y + F1 * c[q].y + F0 * d[q].y;
      dst[2] = F0 * a[q].z + F1 * bb[q].z + F1 * c[q].z + F0 * d[q].z;
      dst[3] = F0 * a[q].w + F1 * bb[q].w + F1 * c[q].w + F0 * d[q].w;
    }
    __syncthreads();
    // horizontal + channel-major store: 65 positions x 8 chunks of 8ch
    const int ph = y & 1, r = y >> 1;
    for (int s = tid; s < 520; s += 256) {
      const int p = s >> 3, j = s & 7;
      union { bf16x8 v; unsigned short u[8]; } pk;
#pragma unroll
      for (int k = 0; k < 8; ++k) {
        const float* vp = &vfls[j * 8 + k][p];
        pk.u[k] = f2bf(F0 * vp[0] + F1 * vp[1] + F1 * vp[2] + F0 * vp[3]);
      }
      const int pw = p & 1, cc = p >> 1;
      const size_t off =
          ((((size_t)(n * 2 + ph) * 2 + pw) * 33 + r) * 33 + cc) * 256 + cg * 64 + j * 8;
      *(bf16x8*)(xfp + off) = pk.v;
    }
    __syncthreads();
  }
}

// ---- stage 5: main conv. grid 512 = n(16) x om(4) x pt(8).
// block 256 thr = 4 waves (2x2), 128(M=o) x 128(N=pos) tile, K = 9 taps x 8 k-blocks of 32ch.
__global__ __launch_bounds__(256, 2) void conv_kernel(
    const unsigned short* __restrict__ Amod,
    const unsigned short* __restrict__ xfp,
    const float* __restrict__ bias,
    float* __restrict__ out) {
  __shared__ unsigned short Als[128 * 32];  // [o_row][k] k-contiguous
  __shared__ unsigned short Bls[128 * 32];  // [pos][k]  k-contiguous
  const int b = blockIdx.x;
  const int n = b >> 5;
  const int om = (b >> 3) & 3;
  const int pt = b & 7;
  const int o0 = om << 7;
  const int oh0 = pt << 2;
  const int tid = threadIdx.x;
  const int lane = tid & 63;
  const int wv = tid >> 6;
  const int wm = wv >> 1;   // wave's M half
  const int wp = wv & 1;    // wave's N half
  const int ml = lane & 15;
  const int kq = lane >> 4;

  f32x4 acc[4][4];
  const f32x4 zz = {0.f, 0.f, 0.f, 0.f};
#pragma unroll
  for (int i = 0; i < 4; ++i)
#pragma unroll
    for (int j = 0; j < 4; ++j) acc[i][j] = zz;

  // staging slots: slot s = 16B = (row = s>>2, kgroup = s&3); wave wv covers s in [wv*128, wv*128+128)
  const int s0 = wv * 128 + lane;
  const int s1 = s0 + 64;
  const int r0 = s0 >> 2, g0 = (s0 & 3) * 8;
  const int r1 = s1 >> 2, g1 = (s1 & 3) * 8;
  unsigned short* aL0 = Als + wv * 1024;          // wave-uniform LDS bases
  unsigned short* aL1 = Als + wv * 1024 + 512;
  unsigned short* bL0 = Bls + wv * 1024;
  unsigned short* bL1 = Bls + wv * 1024 + 512;

#pragma unroll 1
  for (int tap = 0; tap < 9; ++tap) {
    const int kh = (tap >= 6) ? 2 : ((tap >= 3) ? 1 : 0);
    const int kw = tap - kh * 3;
    const int ph = kh & 1, dr = kh >> 1;
    const int pw = kw & 1, dc = kw >> 1;
    const unsigned short* Atap = Amod + (((size_t)(n * 9 + tap) * 512 + o0) << 8);
    const unsigned short* Bpl  = xfp + ((size_t)(((n * 2 + ph) * 2 + pw) * 1089) << 8);
    const unsigned short* Ag0 = Atap + ((size_t)r0 << 8) + g0;
    const unsigned short* Ag1 = Atap + ((size_t)r1 << 8) + g1;
    const unsigned short* Bg0 = Bpl + ((size_t)((oh0 + (r0 >> 5) + dr) * 33 + (r0 & 31) + dc) << 8) + g0;
    const unsigned short* Bg1 = Bpl + ((size_t)((oh0 + (r1 >> 5) + dr) * 33 + (r1 & 31) + dc) << 8) + g1;
#pragma unroll 1
    for (int kb = 0; kb < 8; ++kb) {
      const int ko = kb << 5;
      __syncthreads();                       // prev iter done reading LDS
      gload_lds16(Ag0 + ko, aL0);
      gload_lds16(Ag1 + ko, aL1);
      gload_lds16(Bg0 + ko, bL0);
      gload_lds16(Bg1 + ko, bL1);
      __syncthreads();                       // drains vmcnt; LDS tile ready
      bf16x8 af[4], bfv[4];
      const bf16x8* A8 = (const bf16x8*)Als;
      const bf16x8* B8 = (const bf16x8*)Bls;
#pragma unroll
      for (int t = 0; t < 4; ++t) {
        af[t]  = A8[(wm * 64 + t * 16 + ml) * 4 + kq];
        bfv[t] = B8[(wp * 64 + t * 16 + ml) * 4 + kq];
      }
#pragma unroll
      for (int mt = 0; mt < 4; ++mt)
#pragma unroll
        for (int nt = 0; nt < 4; ++nt)
          acc[mt][nt] = __builtin_amdgcn_mfma_f32_16x16x32_bf16(af[mt], bfv[nt], acc[mt][nt], 0, 0, 0);
    }
  }

  // epilogue: C/D layout col=lane&15 (pos), row=(lane>>4)*4+reg (o). bias + lrelu*sqrt2.
#pragma unroll
  for (int mt = 0; mt < 4; ++mt) {
#pragma unroll
    for (int nt = 0; nt < 4; ++nt) {
      const int p = wp * 64 + nt * 16 + ml;
      const int oh = oh0 + (p >> 5), ow = p & 31;
#pragma unroll
      for (int r = 0; r < 4; ++r) {
        const int o = o0 + wm * 64 + mt * 16 + kq * 4 + r;
        float v = acc[mt][nt][r] + bias[o];
        v = (v >= 0.f ? v : 0.2f * v) * 1.41421356237309515f;
        out[(((size_t)n * 512 + o) * 32 + oh) * 32 + ow] = v;
      }
    }
  }
}

extern "C" void kernel_launch(void* const* d_in, const int* in_sizes, int n_in,
                              void* d_out, int out_size, void* d_ws, size_t ws_size,
                              hipStream_t stream) {
  const float* x  = (const float*)d_in[0];   // [16,256,64,64]
  const float* w  = (const float*)d_in[1];   // [16,512]
  const float* aw = (const float*)d_in[2];   // [256,512]
  const float* ab = (const float*)d_in[3];   // [256]
  const float* wt = (const float*)d_in[4];   // [512,256,3,3]
  const float* bs = (const float*)d_in[5];   // [512]
  float* out = (float*)d_out;                // [16,512,32,32]

  char* ws = (char*)d_ws;
  float* styles        = (float*)(ws);                       // 16*256*4   = 16 KB
  float* dcoefs        = (float*)(ws + 16384);               // 16*512*4   = 32 KB
  float* wsq           = (float*)(ws + 49152);               // 512*256*4  = 512 KB
  unsigned short* Amod = (unsigned short*)(ws + 573440);     // 16*9*512*256*2 = 37.75 MB
  unsigned short* xfp  = (unsigned short*)(ws + 38322176);   // 16*2*2*33*33*256*2 = 35.68 MB
  // total ws need ~74 MB

  styles_kernel<<<dim3(16),   dim3(256), 0, stream>>>(w, aw, ab, styles);
  wsq_kernel   <<<dim3(512),  dim3(256), 0, stream>>>(wt, wsq);
  dcoefs_kernel<<<dim3(16),   dim3(512), 0, stream>>>(wsq, styles, dcoefs);
  modw_kernel  <<<dim3(8192), dim3(256), 0, stream>>>(wt, styles, dcoefs, Amod);
  blur_kernel  <<<dim3(320),  dim3(256), 0, stream>>>(x, xfp);
  conv_kernel  <<<dim3(512),  dim3(256), 0, stream>>>(Amod, xfp, bs, out);
}

// Round 3
// 296.575 us; speedup vs baseline: 2.3072x; 1.0495x over previous
//
#include <hip/hip_runtime.h>
#include <cstdint>
#include <cstddef>

// ---------------------------------------------------------------------------
// StyleDownBlock: styles -> demod -> (blur4x4 ∘ conv3x3 stride2 grouped) -> lrelu
// N=16, I=256, O=512, H=W=64, out 16x512x32x32 fp32.
// R2->R3: xfp layout now [cg4][n][ph][pw][r33][c33][ch64] (dense blur writes,
// was 3.2x write inflation); blur 1024 blocks (was 320, latency-bound);
// conv double-buffered LDS prefetch (1 barrier/iter); modw LDS-staged.
// ---------------------------------------------------------------------------

typedef short bf16x8 __attribute__((ext_vector_type(8)));
typedef float f32x4  __attribute__((ext_vector_type(4)));

#define CGSTR 4460544   // per-cg stride in xfp: 16n * 4planes * 33*33 * 64ch
#define NSTR  278784    // per-n stride within cg: 4 * 1089 * 64
#define PLSTR 69696     // per-plane stride: 1089 * 64

__device__ __forceinline__ unsigned short f2bf(float f) {
  union { float f; unsigned u; } v; v.f = f;
  unsigned r = (v.u + 0x7FFFu + ((v.u >> 16) & 1u)) >> 16;  // RNE
  return (unsigned short)r;
}

__device__ __forceinline__ void gload_lds16(const void* g, void* l) {
  __builtin_amdgcn_global_load_lds((const __attribute__((address_space(1))) void*)g,
                                   (__attribute__((address_space(3))) void*)l,
                                   16, 0, 0);
}

// ---- stage 1: styles[n,i] = dot(w[n,:], affine_w[i,:])/sqrt(512) + affine_b[i]
__global__ void styles_kernel(const float* __restrict__ w, const float* __restrict__ aw,
                              const float* __restrict__ ab, float* __restrict__ styles) {
  const int n = blockIdx.x;      // 16
  const int i = threadIdx.x;     // 256
  const float4* wr = (const float4*)(w + (size_t)n * 512);
  const float4* ar = (const float4*)(aw + (size_t)i * 512);
  float acc = 0.f;
#pragma unroll 4
  for (int k = 0; k < 128; ++k) {
    float4 a = wr[k], c = ar[k];
    acc += a.x * c.x + a.y * c.y + a.z * c.z + a.w * c.w;
  }
  styles[n * 256 + i] = acc * 0.04419417382415922f + ab[i];  // 1/sqrt(512)
}

// ---- stage 2a: wsq[o,i] = sum_k weight[o,i,k]^2
__global__ void wsq_kernel(const float* __restrict__ wt, float* __restrict__ wsq) {
  const int o = blockIdx.x;      // 512
  const int i = threadIdx.x;     // 256
  const float* p = wt + ((size_t)o * 256 + i) * 9;
  float s = 0.f;
#pragma unroll
  for (int k = 0; k < 9; ++k) s += p[k] * p[k];
  wsq[o * 256 + i] = s;
}

// ---- stage 2b: dcoefs[n,o] = rsqrt(sum_i wsq[o,i]*styles[n,i]^2 + 1e-8)
__global__ void dcoefs_kernel(const float* __restrict__ wsq, const float* __restrict__ styles,
                              float* __restrict__ dcoefs) {
  __shared__ float st2[256];
  const int n = blockIdx.x;      // 16
  const int t = threadIdx.x;     // 512
  if (t < 256) { float s = styles[n * 256 + t]; st2[t] = s * s; }
  __syncthreads();
  const float4* wr = (const float4*)(wsq + (size_t)t * 256);
  const float4* sr = (const float4*)st2;
  float acc = 0.f;
#pragma unroll 4
  for (int k = 0; k < 64; ++k) {
    float4 a = wr[k], c = sr[k];
    acc += a.x * c.x + a.y * c.y + a.z * c.z + a.w * c.w;
  }
  dcoefs[n * 512 + t] = 1.0f / sqrtf(acc + 1e-8f);
}

// ---- stage 3 (R3): one block per o; weight row staged in LDS once.
// Amod[n][tap][o][i] = bf16(weight[o,i,8-tap] * styles[n,i] * dcoefs[n,o])
__global__ __launch_bounds__(256) void modw_kernel(
    const float* __restrict__ wt, const float* __restrict__ styles,
    const float* __restrict__ dcoefs, unsigned short* __restrict__ Amod) {
  __shared__ float wls[2304];
  const int o = blockIdx.x;      // 512
  const int t = threadIdx.x;     // 256
  const float* src = wt + (size_t)o * 2304;
#pragma unroll
  for (int k = 0; k < 9; ++k) wls[t + k * 256] = src[t + k * 256];
  __syncthreads();
  float wv9[9];
#pragma unroll
  for (int k = 0; k < 9; ++k) wv9[k] = wls[t * 9 + k];
#pragma unroll 1
  for (int n = 0; n < 16; ++n) {
    const float sd = styles[n * 256 + t] * dcoefs[n * 512 + o];
#pragma unroll
    for (int tap = 0; tap < 9; ++tap)
      Amod[((size_t)(n * 9 + tap) * 512 + o) * 256 + t] = f2bf(wv9[8 - tap] * sd);
  }
}

// ---- stage 4 (R3): separable 4x4 blur, pad 2, bf16 out,
// layout xfp[cg][n][ph][pw][r(33)][c(33)][64ch] = xf[n, cg*64+ch, 2r+ph, 2c+pw].
// Grid: 16n x 16rg(4 rows, last does 5) x 4cg = 1024 blocks, 256 thr.
__global__ __launch_bounds__(256) void blur_kernel(const float* __restrict__ x,
                                                   unsigned short* __restrict__ xfp) {
  __shared__ float vfls[64][69];
  const int b = blockIdx.x;
  const int n = b >> 6;
  const int rem = b & 63;
  const int rg = rem >> 2;              // 0..15
  const int cg = rem & 3;
  const int tid = threadIdx.x;
  const int ch = tid >> 2;              // 0..63 local channel
  const int col0 = (tid & 3) * 16;      // 16-col strip
  const float* xin = x + (((size_t)(n * 256 + cg * 64 + ch)) << 12);
  const int ybase = rg * 4;
  const int ylim = (rg == 15) ? 5 : 4;
  const float F0 = 0.125f, F1 = 0.375f;
  const size_t obase = (size_t)(cg * 16 + n) * 4 * PLSTR;

  float4 ring[4][4];
  auto loadrow = [&](int row) {
    const int slot = row & 3;
    if ((unsigned)row < 64u) {
      const float4* p = (const float4*)(xin + row * 64 + col0);
#pragma unroll
      for (int q = 0; q < 4; ++q) ring[slot][q] = p[q];
    } else {
      const float4 z = {0.f, 0.f, 0.f, 0.f};
#pragma unroll
      for (int q = 0; q < 4; ++q) ring[slot][q] = z;
    }
  };
  loadrow(ybase - 2); loadrow(ybase - 1); loadrow(ybase);

  if ((tid & 3) == 0) { vfls[ch][0] = 0.f; vfls[ch][1] = 0.f; }
  if ((tid & 3) == 3) { vfls[ch][66] = 0.f; vfls[ch][67] = 0.f; vfls[ch][68] = 0.f; }

  for (int yy = 0; yy < ylim; ++yy) {
    const int y = ybase + yy;           // 0..64
    loadrow(y + 1);
    const float4* a = ring[(y + 2) & 3];
    const float4* bb = ring[(y + 3) & 3];
    const float4* c = ring[y & 3];
    const float4* d = ring[(y + 1) & 3];
#pragma unroll
    for (int q = 0; q < 4; ++q) {
      float* dst = &vfls[ch][2 + col0 + q * 4];
      dst[0] = F0 * a[q].x + F1 * bb[q].x + F1 * c[q].x + F0 * d[q].x;
      dst[1] = F0 * a[q].y + F1 * bb[q].y + F1 * c[q].y + F0 * d[q].y;
      dst[2] = F0 * a[q].z + F1 * bb[q].z + F1 * c[q].z + F0 * d[q].z;
      dst[3] = F0 * a[q].w + F1 * bb[q].w + F1 * c[q].w + F0 * d[q].w;
    }
    __syncthreads();
    // horizontal + channel-major repack: 65 positions x 8 chunks of 8ch
    const int ph = y & 1, r = y >> 1;
    for (int s = tid; s < 520; s += 256) {
      const int p = s >> 3, j = s & 7;
      union { bf16x8 v; unsigned short u[8]; } pk;
#pragma unroll
      for (int k = 0; k < 8; ++k) {
        const float* vp = &vfls[j * 8 + k][p];
        pk.u[k] = f2bf(F0 * vp[0] + F1 * vp[1] + F1 * vp[2] + F0 * vp[3]);
      }
      const int pw = p & 1, cc = p >> 1;
      const size_t off = obase + (size_t)(ph * 2 + pw) * PLSTR + (r * 33 + cc) * 64 + j * 8;
      *(bf16x8*)(xfp + off) = pk.v;
    }
    __syncthreads();
  }
}

// ---- stage 5 (R3): implicit GEMM conv, double-buffered LDS prefetch.
// grid 512: idx = pt*64 + (n*4+om) so all 8 pt sharing an A-slice land on one XCD.
// 128(M=o) x 128(N=pos) tile, K = 72 blocks of 32 (9 taps x 8 kb).
__global__ __launch_bounds__(256) void conv_kernel(
    const unsigned short* __restrict__ Amod,
    const unsigned short* __restrict__ xfp,
    const float* __restrict__ bias,
    float* __restrict__ out) {
  __shared__ unsigned short As0[4096], As1[4096];  // 8KB each
  __shared__ unsigned short Bs0[4096], Bs1[4096];
  const int idx = blockIdx.x;
  const int pt = idx >> 6;
  const int P = idx & 63;
  const int n = P >> 2;
  const int om = P & 3;
  const int o0 = om << 7;
  const int oh0 = pt << 2;
  const int tid = threadIdx.x;
  const int lane = tid & 63;
  const int wv = tid >> 6;
  const int wm = wv >> 1;
  const int wp = wv & 1;
  const int ml = lane & 15;
  const int kq = lane >> 4;

  f32x4 acc[4][4];
  const f32x4 zz = {0.f, 0.f, 0.f, 0.f};
#pragma unroll
  for (int i = 0; i < 4; ++i)
#pragma unroll
    for (int j = 0; j < 4; ++j) acc[i][j] = zz;

  const int s0 = wv * 128 + lane, s1 = s0 + 64;
  const int r0 = s0 >> 2, g0 = (s0 & 3) * 8;
  const int r1 = s1 >> 2, g1 = (s1 & 3) * 8;
  const unsigned short* Abase = Amod + (size_t)n * 9 * 131072;
  const int aoff0 = (o0 + r0) * 256 + g0;
  const int aoff1 = (o0 + r1) * 256 + g1;
  const int row0 = oh0 + (r0 >> 5), col0 = r0 & 31;
  const int row1 = oh0 + (r1 >> 5), col1 = r1 & 31;
  const size_t nB = (size_t)n * NSTR;

  auto stage = [&](int kt, unsigned short* As, unsigned short* Bs) {
    const int tap = kt >> 3, kb = kt & 7;
    const int kh = (tap * 11) >> 5;           // tap/3
    const int kw = tap - kh * 3;
    const int ph = kh & 1, dr = kh >> 1;
    const int pw = kw & 1, dc = kw >> 1;
    const unsigned short* At = Abase + tap * 131072 + kb * 32;
    gload_lds16(At + aoff0, As + wv * 1024);
    gload_lds16(At + aoff1, As + wv * 1024 + 512);
    const unsigned short* Bt = xfp + (size_t)(kb >> 1) * CGSTR + nB +
                               (size_t)(ph * 2 + pw) * PLSTR + (kb & 1) * 32;
    gload_lds16(Bt + ((row0 + dr) * 33 + col0 + dc) * 64 + g0, Bs + wv * 1024);
    gload_lds16(Bt + ((row1 + dr) * 33 + col1 + dc) * 64 + g1, Bs + wv * 1024 + 512);
  };
  auto compute = [&](const unsigned short* As, const unsigned short* Bs) {
    bf16x8 af[4], bfv[4];
    const bf16x8* A8 = (const bf16x8*)As;
    const bf16x8* B8 = (const bf16x8*)Bs;
#pragma unroll
    for (int t = 0; t < 4; ++t) {
      af[t]  = A8[(wm * 64 + t * 16 + ml) * 4 + kq];
      bfv[t] = B8[(wp * 64 + t * 16 + ml) * 4 + kq];
    }
#pragma unroll
    for (int mt = 0; mt < 4; ++mt)
#pragma unroll
      for (int nt = 0; nt < 4; ++nt)
        acc[mt][nt] = __builtin_amdgcn_mfma_f32_16x16x32_bf16(af[mt], bfv[nt], acc[mt][nt], 0, 0, 0);
  };

  stage(0, As0, Bs0);
#pragma unroll 1
  for (int kt = 0; kt < 72; kt += 2) {
    __syncthreads();                    // tile kt resident in buf0
    stage(kt + 1, As1, Bs1);            // prefetch overlaps compute
    compute(As0, Bs0);
    __syncthreads();                    // tile kt+1 resident in buf1
    if (kt + 2 < 72) stage(kt + 2, As0, Bs0);
    compute(As1, Bs1);
  }

  // epilogue: C/D layout col=lane&15 (pos), row=(lane>>4)*4+reg (o). bias + lrelu*sqrt2.
#pragma unroll
  for (int mt = 0; mt < 4; ++mt) {
#pragma unroll
    for (int nt = 0; nt < 4; ++nt) {
      const int p = wp * 64 + nt * 16 + ml;
      const int oh = oh0 + (p >> 5), ow = p & 31;
#pragma unroll
      for (int r = 0; r < 4; ++r) {
        const int o = o0 + wm * 64 + mt * 16 + kq * 4 + r;
        float v = acc[mt][nt][r] + bias[o];
        v = (v >= 0.f ? v : 0.2f * v) * 1.41421356237309515f;
        out[(((size_t)n * 512 + o) * 32 + oh) * 32 + ow] = v;
      }
    }
  }
}

extern "C" void kernel_launch(void* const* d_in, const int* in_sizes, int n_in,
                              void* d_out, int out_size, void* d_ws, size_t ws_size,
                              hipStream_t stream) {
  const float* x  = (const float*)d_in[0];   // [16,256,64,64]
  const float* w  = (const float*)d_in[1];   // [16,512]
  const float* aw = (const float*)d_in[2];   // [256,512]
  const float* ab = (const float*)d_in[3];   // [256]
  const float* wt = (const float*)d_in[4];   // [512,256,3,3]
  const float* bs = (const float*)d_in[5];   // [512]
  float* out = (float*)d_out;                // [16,512,32,32]

  char* ws = (char*)d_ws;
  float* styles        = (float*)(ws);                       // 16 KB
  float* dcoefs        = (float*)(ws + 16384);               // 32 KB
  float* wsq           = (float*)(ws + 49152);               // 512 KB
  unsigned short* Amod = (unsigned short*)(ws + 573440);     // 37.75 MB
  unsigned short* xfp  = (unsigned short*)(ws + 38322176);   // 35.68 MB

  styles_kernel<<<dim3(16),   dim3(256), 0, stream>>>(w, aw, ab, styles);
  wsq_kernel   <<<dim3(512),  dim3(256), 0, stream>>>(wt, wsq);
  dcoefs_kernel<<<dim3(16),   dim3(512), 0, stream>>>(wsq, styles, dcoefs);
  modw_kernel  <<<dim3(512),  dim3(256), 0, stream>>>(wt, styles, dcoefs, Amod);
  blur_kernel  <<<dim3(1024), dim3(256), 0, stream>>>(x, xfp);
  conv_kernel  <<<dim3(512),  dim3(256), 0, stream>>>(Amod, xfp, bs, out);
}

// Round 4
// 221.039 us; speedup vs baseline: 3.0957x; 1.3417x over previous
//
#include <hip/hip_runtime.h>
#include <cstdint>
#include <cstddef>

// ---------------------------------------------------------------------------
// StyleDownBlock: styles -> demod -> (blur4x4 ∘ conv3x3 stride2 grouped) -> lrelu
// N=16, I=256, O=512, H=W=64, out 16x512x32x32 fp32.
// R4: modulate-INPUT identity: conv(blur(x), w*s*d) = d ⊙ conv(blur(s*x), w).
//   - styles folded into blur (free), raw bf16 weight as GEMM A (2.36 MB,
//     n-independent, L2-resident), dcoefs applied in conv epilogue (fp32).
//   - Amod (37.75 MB) + modw kernel deleted; ws halves -> poison tax halves.
//   - blur: dbuf LDS stride 71 (conflict-free), 1 barrier/row, reg pipeline,
//     4 blocks/CU.
// ---------------------------------------------------------------------------

typedef short bf16x8 __attribute__((ext_vector_type(8)));
typedef float f32x4  __attribute__((ext_vector_type(4)));

#define CGSTR 4460544   // per-cg stride in xfp: 16n * 4planes * 33*33 * 64ch
#define NSTR  278784    // per-n stride within cg: 4 * 1089 * 64
#define PLSTR 69696     // per-plane stride: 1089 * 64

__device__ __forceinline__ unsigned short f2bf(float f) {
  union { float f; unsigned u; } v; v.f = f;
  unsigned r = (v.u + 0x7FFFu + ((v.u >> 16) & 1u)) >> 16;  // RNE
  return (unsigned short)r;
}

__device__ __forceinline__ void gload_lds16(const void* g, void* l) {
  __builtin_amdgcn_global_load_lds((const __attribute__((address_space(1))) void*)g,
                                   (__attribute__((address_space(3))) void*)l,
                                   16, 0, 0);
}

// ---- stage 1: styles[n,i] = dot(w[n,:], affine_w[i,:])/sqrt(512) + affine_b[i]
__global__ void styles_kernel(const float* __restrict__ w, const float* __restrict__ aw,
                              const float* __restrict__ ab, float* __restrict__ styles) {
  const int n = blockIdx.x;      // 16
  const int i = threadIdx.x;     // 256
  const float4* wr = (const float4*)(w + (size_t)n * 512);
  const float4* ar = (const float4*)(aw + (size_t)i * 512);
  float acc = 0.f;
#pragma unroll 4
  for (int k = 0; k < 128; ++k) {
    float4 a = wr[k], c = ar[k];
    acc += a.x * c.x + a.y * c.y + a.z * c.z + a.w * c.w;
  }
  styles[n * 256 + i] = acc * 0.04419417382415922f + ab[i];  // 1/sqrt(512)
}

// ---- stage 2a: wsq[o,i] = sum_k weight[o,i,k]^2
__global__ void wsq_kernel(const float* __restrict__ wt, float* __restrict__ wsq) {
  const int o = blockIdx.x;      // 512
  const int i = threadIdx.x;     // 256
  const float* p = wt + ((size_t)o * 256 + i) * 9;
  float s = 0.f;
#pragma unroll
  for (int k = 0; k < 9; ++k) s += p[k] * p[k];
  wsq[o * 256 + i] = s;
}

// ---- stage 2b: dcoefs[n,o] = rsqrt(sum_i wsq[o,i]*styles[n,i]^2 + 1e-8)
__global__ void dcoefs_kernel(const float* __restrict__ wsq, const float* __restrict__ styles,
                              float* __restrict__ dcoefs) {
  __shared__ float st2[256];
  const int n = blockIdx.x;      // 16
  const int t = threadIdx.x;     // 512
  if (t < 256) { float s = styles[n * 256 + t]; st2[t] = s * s; }
  __syncthreads();
  const float4* wr = (const float4*)(wsq + (size_t)t * 256);
  const float4* sr = (const float4*)st2;
  float acc = 0.f;
#pragma unroll 4
  for (int k = 0; k < 64; ++k) {
    float4 a = wr[k], c = sr[k];
    acc += a.x * c.x + a.y * c.y + a.z * c.z + a.w * c.w;
  }
  dcoefs[n * 512 + t] = 1.0f / sqrtf(acc + 1e-8f);
}

// ---- stage 3 (R4): raw weight -> bf16, spatially flipped, layout [tap][o][i]
__global__ void wtcvt_kernel(const float* __restrict__ wt, unsigned short* __restrict__ wtb) {
  const int o = blockIdx.x;      // 512
  const int i = threadIdx.x;     // 256
  const float* p = wt + ((size_t)o * 256 + i) * 9;
  float v[9];
#pragma unroll
  for (int k = 0; k < 9; ++k) v[k] = p[k];
#pragma unroll
  for (int tap = 0; tap < 9; ++tap)
    wtb[((size_t)tap * 512 + o) * 256 + i] = f2bf(v[8 - tap]);
}

// ---- stage 4 (R4): separable 4x4 blur of (styles ⊙ x), pad 2, bf16 out,
// layout xfp[cg][n][ph][pw][r(33)][c(33)][64ch] = styles[n,ch']*xf[n, ch', 2r+ph, 2c+pw].
// Grid: 16n x 16rg(4 rows, last 5) x 4cg = 1024 blocks, 256 thr = 64ch x 4 col-strips.
// Dbuf LDS stride 71 (<=2-way banks everywhere), 1 barrier/row, 5-row reg pipeline.
__global__ __launch_bounds__(256, 4) void blur_kernel(const float* __restrict__ x,
                                                      const float* __restrict__ styles,
                                                      unsigned short* __restrict__ xfp) {
  __shared__ float vfls[2][64][71];
  const int b = blockIdx.x;
  const int n = b >> 6;
  const int rem = b & 63;
  const int rg = rem >> 2;              // 0..15
  const int cg = rem & 3;
  const int tid = threadIdx.x;
  const int ch = tid >> 2;              // 0..63 local channel
  const int col0 = (tid & 3) * 16;      // 16-col strip
  const float* xin = x + ((size_t)(n * 256 + cg * 64 + ch) << 12);
  const float s = styles[n * 256 + cg * 64 + ch];
  const float F0s = 0.125f * s, F1s = 0.375f * s;   // styles folded into vertical
  const float F0 = 0.125f, F1 = 0.375f;
  const int ybase = rg * 4;
  const int ylim = (rg == 15) ? 5 : 4;
  const size_t obase = (size_t)(cg * 16 + n) * 4 * PLSTR;

  float4 rA[4], rB[4], rC[4], rD[4], rN[4];
  auto load4 = [&](int row, float4* dst) {
    if ((unsigned)row < 64u) {
      const float4* p = (const float4*)(xin + row * 64 + col0);
      dst[0] = p[0]; dst[1] = p[1]; dst[2] = p[2]; dst[3] = p[3];
    } else {
      const float4 z = {0.f, 0.f, 0.f, 0.f};
      dst[0] = z; dst[1] = z; dst[2] = z; dst[3] = z;
    }
  };
  load4(ybase - 2, rA); load4(ybase - 1, rB); load4(ybase, rC); load4(ybase + 1, rD);

  // pad columns (x-col -2,-1 -> idx 0,1 ; x-col 64,65,66 -> idx 66,67,68)
  if ((tid & 3) == 0) {
    vfls[0][ch][0] = 0.f; vfls[0][ch][1] = 0.f;
    vfls[1][ch][0] = 0.f; vfls[1][ch][1] = 0.f;
  }
  if ((tid & 3) == 3) {
    vfls[0][ch][66] = 0.f; vfls[0][ch][67] = 0.f; vfls[0][ch][68] = 0.f;
    vfls[1][ch][66] = 0.f; vfls[1][ch][67] = 0.f; vfls[1][ch][68] = 0.f;
  }

#pragma unroll 1
  for (int yy = 0; yy < ylim; ++yy) {
    const int y = ybase + yy;           // 0..64
    load4(y + 2, rN);                   // prefetch: lands while we compute/store
    float* vrow = &vfls[yy & 1][ch][2 + col0];
#pragma unroll
    for (int q = 0; q < 4; ++q) {
      vrow[q * 4 + 0] = F0s * rA[q].x + F1s * rB[q].x + F1s * rC[q].x + F0s * rD[q].x;
      vrow[q * 4 + 1] = F0s * rA[q].y + F1s * rB[q].y + F1s * rC[q].y + F0s * rD[q].y;
      vrow[q * 4 + 2] = F0s * rA[q].z + F1s * rB[q].z + F1s * rC[q].z + F0s * rD[q].z;
      vrow[q * 4 + 3] = F0s * rA[q].w + F1s * rB[q].w + F1s * rC[q].w + F0s * rD[q].w;
    }
    __syncthreads();                    // single barrier per row (dbuf)
    const int ph = y & 1, r = y >> 1;
    const float (*vb)[71] = vfls[yy & 1];
#pragma unroll 1
    for (int sI = tid; sI < 520; sI += 256) {
      const int p = sI >> 3, j = sI & 7;
      union { bf16x8 v; unsigned short u[8]; } pk;
#pragma unroll
      for (int k = 0; k < 8; ++k) {
        const float* vp = &vb[j * 8 + k][p];
        pk.u[k] = f2bf(F0 * vp[0] + F1 * vp[1] + F1 * vp[2] + F0 * vp[3]);
      }
      const int pw = p & 1, cc = p >> 1;
      const size_t off = obase + (size_t)(ph * 2 + pw) * PLSTR + (r * 33 + cc) * 64 + j * 8;
      *(bf16x8*)(xfp + off) = pk.v;
    }
#pragma unroll
    for (int q = 0; q < 4; ++q) { rA[q] = rB[q]; rB[q] = rC[q]; rC[q] = rD[q]; rD[q] = rN[q]; }
  }
}

// ---- stage 5 (R4): implicit GEMM conv, A = raw bf16 weight (shared across n),
// dcoefs applied in epilogue. grid 512: idx = pt*64 + (n*4+om) -> same-A blocks
// land on one XCD. 128(M=o) x 128(N=pos) tile, K = 72 x 32 (9 taps x 8 kb).
__global__ __launch_bounds__(256) void conv_kernel(
    const unsigned short* __restrict__ wtb,
    const unsigned short* __restrict__ xfp,
    const float* __restrict__ dcoefs,
    const float* __restrict__ bias,
    float* __restrict__ out) {
  __shared__ unsigned short As0[4096], As1[4096];  // 8KB each
  __shared__ unsigned short Bs0[4096], Bs1[4096];
  const int idx = blockIdx.x;
  const int pt = idx >> 6;
  const int P = idx & 63;
  const int n = P >> 2;
  const int om = P & 3;
  const int o0 = om << 7;
  const int oh0 = pt << 2;
  const int tid = threadIdx.x;
  const int lane = tid & 63;
  const int wv = tid >> 6;
  const int wm = wv >> 1;
  const int wp = wv & 1;
  const int ml = lane & 15;
  const int kq = lane >> 4;

  f32x4 acc[4][4];
  const f32x4 zz = {0.f, 0.f, 0.f, 0.f};
#pragma unroll
  for (int i = 0; i < 4; ++i)
#pragma unroll
    for (int j = 0; j < 4; ++j) acc[i][j] = zz;

  const int s0 = wv * 128 + lane, s1 = s0 + 64;
  const int r0 = s0 >> 2, g0 = (s0 & 3) * 8;
  const int r1 = s1 >> 2, g1 = (s1 & 3) * 8;
  const int aoff0 = (o0 + r0) * 256 + g0;
  const int aoff1 = (o0 + r1) * 256 + g1;
  const int row0 = oh0 + (r0 >> 5), col0 = r0 & 31;
  const int row1 = oh0 + (r1 >> 5), col1 = r1 & 31;
  const size_t nB = (size_t)n * NSTR;

  auto stage = [&](int kt, unsigned short* As, unsigned short* Bs) {
    const int tap = kt >> 3, kb = kt & 7;
    const int kh = (tap * 11) >> 5;           // tap/3
    const int kw = tap - kh * 3;
    const int ph = kh & 1, dr = kh >> 1;
    const int pw = kw & 1, dc = kw >> 1;
    const unsigned short* At = wtb + tap * 131072 + kb * 32;
    gload_lds16(At + aoff0, As + wv * 1024);
    gload_lds16(At + aoff1, As + wv * 1024 + 512);
    const unsigned short* Bt = xfp + (size_t)(kb >> 1) * CGSTR + nB +
                               (size_t)(ph * 2 + pw) * PLSTR + (kb & 1) * 32;
    gload_lds16(Bt + ((row0 + dr) * 33 + col0 + dc) * 64 + g0, Bs + wv * 1024);
    gload_lds16(Bt + ((row1 + dr) * 33 + col1 + dc) * 64 + g1, Bs + wv * 1024 + 512);
  };
  auto compute = [&](const unsigned short* As, const unsigned short* Bs) {
    bf16x8 af[4], bfv[4];
    const bf16x8* A8 = (const bf16x8*)As;
    const bf16x8* B8 = (const bf16x8*)Bs;
#pragma unroll
    for (int t = 0; t < 4; ++t) {
      af[t]  = A8[(wm * 64 + t * 16 + ml) * 4 + kq];
      bfv[t] = B8[(wp * 64 + t * 16 + ml) * 4 + kq];
    }
#pragma unroll
    for (int mt = 0; mt < 4; ++mt)
#pragma unroll
      for (int nt = 0; nt < 4; ++nt)
        acc[mt][nt] = __builtin_amdgcn_mfma_f32_16x16x32_bf16(af[mt], bfv[nt], acc[mt][nt], 0, 0, 0);
  };

  stage(0, As0, Bs0);
#pragma unroll 1
  for (int kt = 0; kt < 72; kt += 2) {
    __syncthreads();                    // tile kt resident in buf0
    stage(kt + 1, As1, Bs1);            // prefetch overlaps compute
    compute(As0, Bs0);
    __syncthreads();                    // tile kt+1 resident in buf1
    if (kt + 2 < 72) stage(kt + 2, As0, Bs0);
    compute(As1, Bs1);
  }

  // epilogue: C/D layout col=lane&15 (pos), row=(lane>>4)*4+reg (o).
  // v = acc*dcoef + bias -> lrelu*sqrt2.
  f32x4 dc4[4], bi4[4];
#pragma unroll
  for (int mt = 0; mt < 4; ++mt) {
    const int ob = o0 + wm * 64 + mt * 16 + kq * 4;
    dc4[mt] = *(const f32x4*)(dcoefs + n * 512 + ob);
    bi4[mt] = *(const f32x4*)(bias + ob);
  }
#pragma unroll
  for (int mt = 0; mt < 4; ++mt) {
#pragma unroll
    for (int nt = 0; nt < 4; ++nt) {
      const int p = wp * 64 + nt * 16 + ml;
      const int oh = oh0 + (p >> 5), ow = p & 31;
#pragma unroll
      for (int r = 0; r < 4; ++r) {
        const int o = o0 + wm * 64 + mt * 16 + kq * 4 + r;
        float v = acc[mt][nt][r] * dc4[mt][r] + bi4[mt][r];
        v = (v >= 0.f ? v : 0.2f * v) * 1.41421356237309515f;
        out[(((size_t)n * 512 + o) * 32 + oh) * 32 + ow] = v;
      }
    }
  }
}

extern "C" void kernel_launch(void* const* d_in, const int* in_sizes, int n_in,
                              void* d_out, int out_size, void* d_ws, size_t ws_size,
                              hipStream_t stream) {
  const float* x  = (const float*)d_in[0];   // [16,256,64,64]
  const float* w  = (const float*)d_in[1];   // [16,512]
  const float* aw = (const float*)d_in[2];   // [256,512]
  const float* ab = (const float*)d_in[3];   // [256]
  const float* wt = (const float*)d_in[4];   // [512,256,3,3]
  const float* bs = (const float*)d_in[5];   // [512]
  float* out = (float*)d_out;                // [16,512,32,32]

  char* ws = (char*)d_ws;
  float* styles        = (float*)(ws);                       // 16 KB
  float* dcoefs        = (float*)(ws + 16384);               // 32 KB
  float* wsq           = (float*)(ws + 49152);               // 512 KB
  unsigned short* wtb  = (unsigned short*)(ws + 573440);     // 9*512*256*2 = 2.36 MB
  unsigned short* xfp  = (unsigned short*)(ws + 2932736);    // 35.68 MB  (total ~38.6 MB)

  styles_kernel<<<dim3(16),   dim3(256), 0, stream>>>(w, aw, ab, styles);
  wsq_kernel   <<<dim3(512),  dim3(256), 0, stream>>>(wt, wsq);
  dcoefs_kernel<<<dim3(16),   dim3(512), 0, stream>>>(wsq, styles, dcoefs);
  wtcvt_kernel <<<dim3(512),  dim3(256), 0, stream>>>(wt, wtb);
  blur_kernel  <<<dim3(1024), dim3(256), 0, stream>>>(x, styles, xfp);
  conv_kernel  <<<dim3(512),  dim3(256), 0, stream>>>(wtb, xfp, dcoefs, bs, out);
}

// Round 6
// 211.219 us; speedup vs baseline: 3.2396x; 1.0465x over previous
//
#include <hip/hip_runtime.h>
#include <cstdint>
#include <cstddef>

// ---------------------------------------------------------------------------
// StyleDownBlock: styles -> demod -> (blur4x4 ∘ conv3x3 stride2 grouped) -> lrelu
// N=16, I=256, O=512, H=W=64, out 16x512x32x32 fp32.
// R5: conv block order om*128+pt*16+n -> XCD = n%8 (all om-blocks sharing a
//   B-tile on ONE XCD; was 4 XCDs -> 4x xfp re-fetch = 150MB). Blur horizontal
//   now in registers (shfl neighbor exchange), bf16 LDS transpose pad only.
//   wsq merged into wtcvt.
// R6: fix stack OOB in blur (ve[19] read for p=64 tap; need explicit zero pad
//   slot -> ve[20] with ve[19]=0). R5 logic otherwise unchanged.
// ---------------------------------------------------------------------------

typedef short bf16x8 __attribute__((ext_vector_type(8)));
typedef float f32x4  __attribute__((ext_vector_type(4)));

#define CGSTR 4460544   // per-cg stride in xfp: 16n * 4planes * 33*33 * 64ch
#define NSTR  278784    // per-n stride within cg: 4 * 1089 * 64
#define PLSTR 69696     // per-plane stride: 1089 * 64

__device__ __forceinline__ unsigned short f2bf(float f) {
  union { float f; unsigned u; } v; v.f = f;
  unsigned r = (v.u + 0x7FFFu + ((v.u >> 16) & 1u)) >> 16;  // RNE
  return (unsigned short)r;
}

__device__ __forceinline__ void gload_lds16(const void* g, void* l) {
  __builtin_amdgcn_global_load_lds((const __attribute__((address_space(1))) void*)g,
                                   (__attribute__((address_space(3))) void*)l,
                                   16, 0, 0);
}

// ---- stage 1: styles[n,i] = dot(w[n,:], affine_w[i,:])/sqrt(512) + affine_b[i]
__global__ void styles_kernel(const float* __restrict__ w, const float* __restrict__ aw,
                              const float* __restrict__ ab, float* __restrict__ styles) {
  const int n = blockIdx.x;      // 16
  const int i = threadIdx.x;     // 256
  const float4* wr = (const float4*)(w + (size_t)n * 512);
  const float4* ar = (const float4*)(aw + (size_t)i * 512);
  float acc = 0.f;
#pragma unroll 4
  for (int k = 0; k < 128; ++k) {
    float4 a = wr[k], c = ar[k];
    acc += a.x * c.x + a.y * c.y + a.z * c.z + a.w * c.w;
  }
  styles[n * 256 + i] = acc * 0.04419417382415922f + ab[i];  // 1/sqrt(512)
}

// ---- stage 2: one pass over weight: wsq[o,i] AND flipped bf16 wtb[tap][o][i]
__global__ void wtcvt_kernel(const float* __restrict__ wt, unsigned short* __restrict__ wtb,
                             float* __restrict__ wsq) {
  const int o = blockIdx.x;      // 512
  const int i = threadIdx.x;     // 256
  const float* p = wt + ((size_t)o * 256 + i) * 9;
  float v[9];
  float s = 0.f;
#pragma unroll
  for (int k = 0; k < 9; ++k) { v[k] = p[k]; s += v[k] * v[k]; }
  wsq[o * 256 + i] = s;
#pragma unroll
  for (int tap = 0; tap < 9; ++tap)
    wtb[((size_t)tap * 512 + o) * 256 + i] = f2bf(v[8 - tap]);
}

// ---- stage 3: dcoefs[n,o] = rsqrt(sum_i wsq[o,i]*styles[n,i]^2 + 1e-8)
__global__ void dcoefs_kernel(const float* __restrict__ wsq, const float* __restrict__ styles,
                              float* __restrict__ dcoefs) {
  __shared__ float st2[256];
  const int n = blockIdx.x;      // 16
  const int t = threadIdx.x;     // 512
  if (t < 256) { float s = styles[n * 256 + t]; st2[t] = s * s; }
  __syncthreads();
  const float4* wr = (const float4*)(wsq + (size_t)t * 256);
  const float4* sr = (const float4*)st2;
  float acc = 0.f;
#pragma unroll 4
  for (int k = 0; k < 64; ++k) {
    float4 a = wr[k], c = sr[k];
    acc += a.x * c.x + a.y * c.y + a.z * c.z + a.w * c.w;
  }
  dcoefs[n * 512 + t] = 1.0f / sqrtf(acc + 1e-8f);
}

// ---- stage 4: separable 4x4 blur of (styles ⊙ x), pad 2, bf16 out,
// layout xfp[cg][n][ph][pw][r(33)][c(33)][64ch].
// Grid: 16n x 16rg x 4cg = 1024 blocks, 256 thr = 64ch x 4 col-strips.
// Vertical AND horizontal in registers (shfl exchange for strip boundaries);
// bf16 results -> dbuf LDS pad -> cooperative channel-major 16B stores.
__global__ __launch_bounds__(256, 4) void blur_kernel(const float* __restrict__ x,
                                                      const float* __restrict__ styles,
                                                      unsigned short* __restrict__ xfp) {
  __shared__ unsigned short shls[2][64][68];
  const int b = blockIdx.x;
  const int n = b >> 6;
  const int rem = b & 63;
  const int rg = rem >> 2;              // 0..15
  const int cg = rem & 3;
  const int tid = threadIdx.x;
  const int ch = tid >> 2;              // 0..63 local channel
  const int s4 = tid & 3;               // col strip
  const int col0 = s4 * 16;
  const float* xin = x + ((size_t)(n * 256 + cg * 64 + ch) << 12);
  const float sv = styles[n * 256 + cg * 64 + ch];
  const float F0s = 0.125f * sv, F1s = 0.375f * sv;   // styles folded in
  const float F0 = 0.125f, F1 = 0.375f;
  const int ybase = rg * 4;
  const int ylim = (rg == 15) ? 5 : 4;
  const size_t obase = (size_t)(cg * 16 + n) * 4 * PLSTR;

  float4 rA[4], rB[4], rC[4], rD[4], rN[4];
  auto load4 = [&](int row, float4* dst) {
    if ((unsigned)row < 64u) {
      const float4* p = (const float4*)(xin + row * 64 + col0);
      dst[0] = p[0]; dst[1] = p[1]; dst[2] = p[2]; dst[3] = p[3];
    } else {
      const float4 z = {0.f, 0.f, 0.f, 0.f};
      dst[0] = z; dst[1] = z; dst[2] = z; dst[3] = z;
    }
  };
  load4(ybase - 2, rA); load4(ybase - 1, rB); load4(ybase, rC); load4(ybase + 1, rD);

#pragma unroll 1
  for (int yy = 0; yy < ylim; ++yy) {
    const int y = ybase + yy;           // 0..64
    load4(y + 2, rN);                   // prefetch next row
    // vertical filter (styles folded) -> ve[2..17] = cols col0..col0+15;
    // ve[0..1] from left neighbor, ve[18] from right, ve[19] = zero pad (x col 65+)
    float ve[20];
#pragma unroll
    for (int q = 0; q < 4; ++q) {
      ve[2 + q * 4 + 0] = F0s * rA[q].x + F1s * rB[q].x + F1s * rC[q].x + F0s * rD[q].x;
      ve[2 + q * 4 + 1] = F0s * rA[q].y + F1s * rB[q].y + F1s * rC[q].y + F0s * rD[q].y;
      ve[2 + q * 4 + 2] = F0s * rA[q].z + F1s * rB[q].z + F1s * rC[q].z + F0s * rD[q].z;
      ve[2 + q * 4 + 3] = F0s * rA[q].w + F1s * rB[q].w + F1s * rC[q].w + F0s * rD[q].w;
    }
    float vm2 = __shfl_up(ve[16], 1);   // left strip's col0-2
    float vm1 = __shfl_up(ve[17], 1);   // left strip's col0-1
    float vp1 = __shfl_down(ve[2], 1);  // right strip's col0+16
    if (s4 == 0) { vm2 = 0.f; vm1 = 0.f; }
    if (s4 == 3) vp1 = 0.f;
    ve[0] = vm2; ve[1] = vm1; ve[18] = vp1; ve[19] = 0.f;
    // horizontal in regs: out[p=col0+pl] = F0*ve[pl]+F1*ve[pl+1]+F1*ve[pl+2]+F0*ve[pl+3]
    unsigned short hv[17];
#pragma unroll
    for (int pl = 0; pl < 17; ++pl)
      hv[pl] = f2bf(F0 * ve[pl] + F1 * ve[pl + 1] + F1 * ve[pl + 2] + F0 * ve[pl + 3]);
    unsigned short (*sh)[68] = shls[yy & 1];
    unsigned* dst32 = (unsigned*)&sh[ch][col0];
#pragma unroll
    for (int q = 0; q < 8; ++q)
      dst32[q] = (unsigned)hv[2 * q] | ((unsigned)hv[2 * q + 1] << 16);
    if (s4 == 3) sh[ch][64] = hv[16];   // p=64 (pw=0, c=32)
    __syncthreads();
    // cooperative channel-major store: 65 positions x 8 chunks of 8ch
    const int ph = y & 1, r = y >> 1;
#pragma unroll 1
    for (int sI = tid; sI < 520; sI += 256) {
      const int p = sI >> 3, j = sI & 7;
      union { bf16x8 vv; unsigned short u[8]; } pk;
#pragma unroll
      for (int k = 0; k < 8; ++k) pk.u[k] = sh[j * 8 + k][p];
      const int pw = p & 1, cc = p >> 1;
      const size_t off = obase + (size_t)(ph * 2 + pw) * PLSTR + (r * 33 + cc) * 64 + j * 8;
      *(bf16x8*)(xfp + off) = pk.vv;
    }
#pragma unroll
    for (int q = 0; q < 4; ++q) { rA[q] = rB[q]; rB[q] = rC[q]; rC[q] = rD[q]; rD[q] = rN[q]; }
  }
}

// ---- stage 5: implicit GEMM conv, A = raw bf16 weight (L2-resident),
// dcoefs in epilogue. grid 512: idx = om*128 + pt*16 + n -> XCD = n%8, so each
// n's xfp tile lives on exactly one XCD's L2 (B re-fetch 4x -> ~1x).
// 128(M=o) x 128(N=pos) tile, K = 72 x 32 (9 taps x 8 kb), dbuf LDS prefetch.
__global__ __launch_bounds__(256) void conv_kernel(
    const unsigned short* __restrict__ wtb,
    const unsigned short* __restrict__ xfp,
    const float* __restrict__ dcoefs,
    const float* __restrict__ bias,
    float* __restrict__ out) {
  __shared__ unsigned short As0[4096], As1[4096];  // 8KB each
  __shared__ unsigned short Bs0[4096], Bs1[4096];
  const int idx = blockIdx.x;
  const int om = idx >> 7;        // 0..3
  const int g = idx & 127;
  const int pt = g >> 4;          // 0..7
  const int n = g & 15;           // XCD = idx%8 = n%8
  const int o0 = om << 7;
  const int oh0 = pt << 2;
  const int tid = threadIdx.x;
  const int lane = tid & 63;
  const int wv = tid >> 6;
  const int wm = wv >> 1;
  const int wp = wv & 1;
  const int ml = lane & 15;
  const int kq = lane >> 4;

  f32x4 acc[4][4];
  const f32x4 zz = {0.f, 0.f, 0.f, 0.f};
#pragma unroll
  for (int i = 0; i < 4; ++i)
#pragma unroll
    for (int j = 0; j < 4; ++j) acc[i][j] = zz;

  const int s0 = wv * 128 + lane, s1 = s0 + 64;
  const int r0 = s0 >> 2, g0 = (s0 & 3) * 8;
  const int r1 = s1 >> 2, g1 = (s1 & 3) * 8;
  const int aoff0 = (o0 + r0) * 256 + g0;
  const int aoff1 = (o0 + r1) * 256 + g1;
  const int row0 = oh0 + (r0 >> 5), col0 = r0 & 31;
  const int row1 = oh0 + (r1 >> 5), col1 = r1 & 31;
  const size_t nB = (size_t)n * NSTR;

  auto stage = [&](int kt, unsigned short* As, unsigned short* Bs) {
    const int tap = kt >> 3, kb = kt & 7;
    const int kh = (tap * 11) >> 5;           // tap/3
    const int kw = tap - kh * 3;
    const int ph = kh & 1, dr = kh >> 1;
    const int pw = kw & 1, dc = kw >> 1;
    const unsigned short* At = wtb + tap * 131072 + kb * 32;
    gload_lds16(At + aoff0, As + wv * 1024);
    gload_lds16(At + aoff1, As + wv * 1024 + 512);
    const unsigned short* Bt = xfp + (size_t)(kb >> 1) * CGSTR + nB +
                               (size_t)(ph * 2 + pw) * PLSTR + (kb & 1) * 32;
    gload_lds16(Bt + ((row0 + dr) * 33 + col0 + dc) * 64 + g0, Bs + wv * 1024);
    gload_lds16(Bt + ((row1 + dr) * 33 + col1 + dc) * 64 + g1, Bs + wv * 1024 + 512);
  };
  auto compute = [&](const unsigned short* As, const unsigned short* Bs) {
    bf16x8 af[4], bfv[4];
    const bf16x8* A8 = (const bf16x8*)As;
    const bf16x8* B8 = (const bf16x8*)Bs;
#pragma unroll
    for (int t = 0; t < 4; ++t) {
      af[t]  = A8[(wm * 64 + t * 16 + ml) * 4 + kq];
      bfv[t] = B8[(wp * 64 + t * 16 + ml) * 4 + kq];
    }
#pragma unroll
    for (int mt = 0; mt < 4; ++mt)
#pragma unroll
      for (int nt = 0; nt < 4; ++nt)
        acc[mt][nt] = __builtin_amdgcn_mfma_f32_16x16x32_bf16(af[mt], bfv[nt], acc[mt][nt], 0, 0, 0);
  };

  stage(0, As0, Bs0);
#pragma unroll 1
  for (int kt = 0; kt < 72; kt += 2) {
    __syncthreads();                    // tile kt resident in buf0
    stage(kt + 1, As1, Bs1);            // prefetch overlaps compute
    compute(As0, Bs0);
    __syncthreads();                    // tile kt+1 resident in buf1
    if (kt + 2 < 72) stage(kt + 2, As0, Bs0);
    compute(As1, Bs1);
  }

  // epilogue: C/D layout col=lane&15 (pos), row=(lane>>4)*4+reg (o).
  // v = acc*dcoef + bias -> lrelu*sqrt2.
  f32x4 dc4[4], bi4[4];
#pragma unroll
  for (int mt = 0; mt < 4; ++mt) {
    const int ob = o0 + wm * 64 + mt * 16 + kq * 4;
    dc4[mt] = *(const f32x4*)(dcoefs + n * 512 + ob);
    bi4[mt] = *(const f32x4*)(bias + ob);
  }
#pragma unroll
  for (int mt = 0; mt < 4; ++mt) {
#pragma unroll
    for (int nt = 0; nt < 4; ++nt) {
      const int p = wp * 64 + nt * 16 + ml;
      const int oh = oh0 + (p >> 5), ow = p & 31;
#pragma unroll
      for (int r = 0; r < 4; ++r) {
        const int o = o0 + wm * 64 + mt * 16 + kq * 4 + r;
        float v = acc[mt][nt][r] * dc4[mt][r] + bi4[mt][r];
        v = (v >= 0.f ? v : 0.2f * v) * 1.41421356237309515f;
        out[(((size_t)n * 512 + o) * 32 + oh) * 32 + ow] = v;
      }
    }
  }
}

extern "C" void kernel_launch(void* const* d_in, const int* in_sizes, int n_in,
                              void* d_out, int out_size, void* d_ws, size_t ws_size,
                              hipStream_t stream) {
  const float* x  = (const float*)d_in[0];   // [16,256,64,64]
  const float* w  = (const float*)d_in[1];   // [16,512]
  const float* aw = (const float*)d_in[2];   // [256,512]
  const float* ab = (const float*)d_in[3];   // [256]
  const float* wt = (const float*)d_in[4];   // [512,256,3,3]
  const float* bs = (const float*)d_in[5];   // [512]
  float* out = (float*)d_out;                // [16,512,32,32]

  char* ws = (char*)d_ws;
  float* styles        = (float*)(ws);                       // 16 KB
  float* dcoefs        = (float*)(ws + 16384);               // 32 KB
  float* wsq           = (float*)(ws + 49152);               // 512 KB
  unsigned short* wtb  = (unsigned short*)(ws + 573440);     // 9*512*256*2 = 2.36 MB
  unsigned short* xfp  = (unsigned short*)(ws + 2932736);    // 35.68 MB  (total ~38.6 MB)

  styles_kernel<<<dim3(16),   dim3(256), 0, stream>>>(w, aw, ab, styles);
  wtcvt_kernel <<<dim3(512),  dim3(256), 0, stream>>>(wt, wtb, wsq);
  dcoefs_kernel<<<dim3(16),   dim3(512), 0, stream>>>(wsq, styles, dcoefs);
  blur_kernel  <<<dim3(1024), dim3(256), 0, stream>>>(x, styles, xfp);
  conv_kernel  <<<dim3(512),  dim3(256), 0, stream>>>(wtb, xfp, dcoefs, bs, out);
}